// Round 12
// baseline (114.417 us; speedup 1.0000x reference)
//
#include <hip/hip_runtime.h>
#include <hip/hip_fp16.h>
#include <math.h>

// Siddon forward projection, 128^3 grid over [-1,1]^3, voxel = 1/64.
// ONE RAY PER WAVE, K=64 alpha-chunks (one per lane), serial incremental
// traversal with packed byte-offset voxel index (validated round 9).
// - perfect intra-wave balance (all lanes share one ray; equal alpha chunks)
// - depth-3 rotating load pipeline (scalars, no arrays) per lane
// - 8 resident waves/SIMD hide the L2-hit latency of the fp16 image
//   (4 MB in workspace -> L2-resident per XCD, validated round 7).

static constexpr float VOX = 0.015625f;   // 2/128, exact power of two
static constexpr float INV_VOX = 64.0f;
static constexpr int   NVOX = 128 * 128 * 128;
static constexpr int   IDX_MASK = 0x3FFFFE;   // even byte offset, < 4 MB

struct TState {
  float alx, aly, alz;   // next-crossing alpha per axis
  float dax, day, daz;   // alpha increment per crossing
  float acur, aend;
  int   idx;             // packed byte offset: ix*2^15 + iy*2^8 + iz*2
  int   dix, diy, diz;   // packed per-crossing deltas (signed)
};

// One Siddon step: returns segment length (0 for padded/degenerate steps),
// issues the (masked, always in-range) image load for this step's voxel.
__device__ __forceinline__ float step_load(const __half* __restrict__ image,
                                           TState& S, float& v) {
  float anext = fminf(fminf(S.alx, S.aly), S.alz);
  float astop = fminf(anext, S.aend);
  float dif   = fmaxf(astop - S.acur, 0.0f);
  int idxm = S.idx & IDX_MASK;
  v = __half2float(*(const __half*)((const char*)image + idxm));
  S.acur = astop;
  bool cx = S.alx <= anext;
  bool cy = S.aly <= anext;
  bool cz = S.alz <= anext;
  S.idx += (cx ? S.dix : 0) + (cy ? S.diy : 0) + (cz ? S.diz : 0);
  S.alx += cx ? S.dax : 0.0f;
  S.aly += cy ? S.day : 0.0f;
  S.alz += cz ? S.daz : 0.0f;
  return dif;
}

// First plane index strictly past astart in walk order, its alpha, the alpha
// increment, the voxel containing astart, and crossing count in (astart,aend].
__device__ __forceinline__ void axis_init(float astart, float aend, float p0,
                                          float ds, float inv,
                                          int& st, int& iv, float& al, float& da,
                                          int& cnt) {
  float ts = (fmaf(astart, ds, p0) + 1.0f) * INV_VOX;
  float te = (fmaf(aend,   ds, p0) + 1.0f) * INV_VOX;
  int ip;
  if (ds > 0.0f) {
    ip = (int)floorf(ts) + 1;
    int il = (int)floorf(te); if (il > 128) il = 128;
    cnt = il - ip + 1; st = 1; iv = ip - 1;
  } else {
    ip = (int)ceilf(ts) - 1;
    int il = (int)ceilf(te); if (il < 0) il = 0;
    cnt = ip - il + 1; st = -1; iv = ip;
  }
  if (cnt < 0) cnt = 0;
  al = (fmaf((float)ip, VOX, -1.0f) - p0) * inv;
  da = VOX * fabsf(inv);
}

// --- image fp32 -> fp16 (workspace) -----------------------------------------
__global__ __launch_bounds__(256) void convert_h(
    const float* __restrict__ img, __half* __restrict__ h)
{
  int i = blockIdx.x * blockDim.x + threadIdx.x;
  int stride = gridDim.x * blockDim.x;
  for (; i < NVOX; i += stride) h[i] = __float2half(img[i]);
}

// --- traversal: one wave per ray ---------------------------------------------
__global__ __launch_bounds__(256) void siddon_fp(
    const __half* __restrict__ image,
    const float* __restrict__ lors,
    float* __restrict__ out, int n)
{
  int ray = (blockIdx.x * blockDim.x + threadIdx.x) >> 6;
  int k   = threadIdx.x & 63;
  if (ray >= n) return;

  const float* L = lors + (long)ray * 6;
  float p0x = L[0], p0y = L[1], p0z = L[2];
  float dx  = L[3] - p0x, dy = L[4] - p0y, dz = L[5] - p0z;

  const float eps = 1e-9f;
  float dsx = (fabsf(dx) < eps) ? eps : dx;
  float dsy = (fabsf(dy) < eps) ? eps : dy;
  float dsz = (fabsf(dz) < eps) ? eps : dz;

  float invx = __builtin_amdgcn_rcpf(dsx);
  float invy = __builtin_amdgcn_rcpf(dsy);
  float invz = __builtin_amdgcn_rcpf(dsz);

  float a0 = (-1.0f - p0x) * invx, a1 = (1.0f - p0x) * invx;
  float axmin = fminf(a0, a1), axmax = fmaxf(a0, a1);
  a0 = (-1.0f - p0y) * invy; a1 = (1.0f - p0y) * invy;
  float aymin = fminf(a0, a1), aymax = fmaxf(a0, a1);
  a0 = (-1.0f - p0z) * invz; a1 = (1.0f - p0z) * invz;
  float azmin = fminf(a0, a1), azmax = fmaxf(a0, a1);

  float amin = fmaxf(fmaxf(axmin, aymin), fmaxf(azmin, 0.0f));
  float amax = fminf(fminf(axmax, aymax), fminf(azmax, 1.0f));

  float acc = 0.0f;
  if (amax > amin) {                   // wave-uniform branch (one ray/wave)
    float s      = (amax - amin) * (1.0f / 64.0f);
    float astart = fmaf((float)k, s, amin);
    float aend   = (k == 63) ? amax : fmaf((float)(k + 1), s, amin);

    TState S;
    S.acur = astart; S.aend = aend;
    int stx, sty, stz, ivx, ivy, ivz, c0, c1, c2;
    axis_init(astart, aend, p0x, dsx, invx, stx, ivx, S.alx, S.dax, c0);
    axis_init(astart, aend, p0y, dsy, invy, sty, ivy, S.aly, S.day, c1);
    axis_init(astart, aend, p0z, dsz, invz, stz, ivz, S.alz, S.daz, c2);
    // ARITHMETIC packing (not OR): exact for transient -1 excursions (r9).
    S.idx = ivx * 32768 + ivy * 256 + ivz * 2;
    S.dix = stx * 32768;  S.diy = sty * 256;  S.diz = stz * 2;

    int nb = c0 + c1 + c2 + 3;         // +1 final partial, +2 cushion (>=3)
    // wave-max trip count; overrun lanes self-neutralize (dif clamps to 0)
    #pragma unroll
    for (int d = 1; d < 64; d <<= 1) {
      int o = __shfl_xor(nb, d);
      nb = (o > nb) ? o : nb;
    }

    float vA, vB, vC;
    float dA = step_load(image, S, vA);
    float dB = step_load(image, S, vB);
    for (int i = 2; i < nb; ++i) {
      float dC = step_load(image, S, vC);
      acc = fmaf(dA, vA, acc);
      dA = dB; vA = vB;
      dB = dC; vB = vC;
    }
    acc = fmaf(dA, vA, acc);
    acc = fmaf(dB, vB, acc);

    acc *= sqrtf(dx * dx + dy * dy + dz * dz);
  }

  // reduce 64 lane partials
  acc += __shfl_xor(acc, 1);
  acc += __shfl_xor(acc, 2);
  acc += __shfl_xor(acc, 4);
  acc += __shfl_xor(acc, 8);
  acc += __shfl_xor(acc, 16);
  acc += __shfl_xor(acc, 32);
  if (k == 0) out[ray] = acc;
}

extern "C" void kernel_launch(void* const* d_in, const int* in_sizes, int n_in,
                              void* d_out, int out_size, void* d_ws, size_t ws_size,
                              hipStream_t stream) {
  const float* image = (const float*)d_in[0];   // [128,128,128] f32
  const float* lors  = (const float*)d_in[1];   // [N,6] f32
  float* out = (float*)d_out;                   // [N] f32
  int n = out_size;

  __half* h = (__half*)d_ws;                    // 4 MB fp16 image
  hipLaunchKernelGGL(convert_h, dim3(2048), dim3(256), 0, stream, image, h);

  // one wave (64 lanes) per ray; 4 waves per 256-thread block
  int grid = (n + 3) / 4;
  hipLaunchKernelGGL(siddon_fp, dim3(grid), dim3(256), 0, stream,
                     h, lors, out, n);
}

// Round 13
// 67.319 us; speedup vs baseline: 1.6996x; 1.6996x over previous
//
#include <hip/hip_runtime.h>
#include <hip/hip_fp16.h>
#include <math.h>

// Siddon forward projection, 128^3 grid over [-1,1]^3, voxel = 1/64.
// K=16 lanes per LOR (alpha chunks), cheap packed-index serial step with
// depth-3 batch-4 load pipeline; fp16 image in workspace (L2-resident).
// Rays are bucket-sorted by crossing count (8 bins, longest first, miss rays
// last) so each wave's 4 rays have similar trip counts. The sort is fully
// deterministic and uses NO returning global atomics (per-block LDS/ballot
// histogram -> single-block scan -> rank-based scatter).

static constexpr float VOX = 0.015625f;   // 2/128, exact power of two
static constexpr float INV_VOX = 64.0f;
static constexpr int   K = 16;
static constexpr int   LOGK = 4;
static constexpr int   NVOX = 128 * 128 * 128;
static constexpr int   IDX_MASK = 0x3FFFFE;   // even byte offset, < 4 MB
static constexpr int   NBINS = 8;             // bin 0 = miss, 1..7 by V>>6

struct TState {
  float alx, aly, alz;   // next-crossing alpha per axis
  float dax, day, daz;   // alpha increment per crossing
  float acur, aend;
  int   idx;             // packed byte offset: ix*2^15 + iy*2^8 + iz*2
  int   dix, diy, diz;   // packed per-crossing deltas (signed)
};

__device__ __forceinline__ void step4(const __half* __restrict__ image,
                                      TState& S, float dif4[4], float v4[4]) {
#pragma unroll
  for (int j = 0; j < 4; ++j) {
    float anext = fminf(fminf(S.alx, S.aly), S.alz);
    float astop = fminf(anext, S.aend);
    float dif   = fmaxf(astop - S.acur, 0.0f);
    dif4[j] = dif;
    // dead/padded steps (dif==0) read line 0 (broadcast), not random lines
    int addr = (dif > 0.0f) ? (S.idx & IDX_MASK) : 0;
    v4[j] = __half2float(*(const __half*)((const char*)image + addr));
    S.acur = astop;
    bool cx = S.alx <= anext;
    bool cy = S.aly <= anext;
    bool cz = S.alz <= anext;
    S.idx += (cx ? S.dix : 0) + (cy ? S.diy : 0) + (cz ? S.diz : 0);
    S.alx += cx ? S.dax : 0.0f;
    S.aly += cy ? S.day : 0.0f;
    S.alz += cz ? S.daz : 0.0f;
  }
}

// First plane index strictly past astart in walk order, its alpha, the alpha
// increment, the voxel containing astart, and crossing count in (astart,aend].
__device__ __forceinline__ void axis_init(float astart, float aend, float p0,
                                          float ds, float inv,
                                          int& st, int& iv, float& al, float& da,
                                          int& cnt) {
  float ts = (fmaf(astart, ds, p0) + 1.0f) * INV_VOX;
  float te = (fmaf(aend,   ds, p0) + 1.0f) * INV_VOX;
  int ip;
  if (ds > 0.0f) {
    ip = (int)floorf(ts) + 1;
    int il = (int)floorf(te); if (il > 128) il = 128;
    cnt = il - ip + 1; st = 1; iv = ip - 1;
  } else {
    ip = (int)ceilf(ts) - 1;
    int il = (int)ceilf(te); if (il < 0) il = 0;
    cnt = ip - il + 1; st = -1; iv = ip;
  }
  if (cnt < 0) cnt = 0;
  al = (fmaf((float)ip, VOX, -1.0f) - p0) * inv;
  da = VOX * fabsf(inv);
}

__device__ __forceinline__ void ray_setup(const float* L,
    float& p0x, float& p0y, float& p0z,
    float& dx, float& dy, float& dz,
    float& dsx, float& dsy, float& dsz,
    float& invx, float& invy, float& invz,
    float& amin, float& amax) {
  p0x = L[0]; p0y = L[1]; p0z = L[2];
  dx = L[3] - p0x; dy = L[4] - p0y; dz = L[5] - p0z;
  const float eps = 1e-9f;
  dsx = (fabsf(dx) < eps) ? eps : dx;
  dsy = (fabsf(dy) < eps) ? eps : dy;
  dsz = (fabsf(dz) < eps) ? eps : dz;
  invx = __builtin_amdgcn_rcpf(dsx);
  invy = __builtin_amdgcn_rcpf(dsy);
  invz = __builtin_amdgcn_rcpf(dsz);
  float a0 = (-1.0f - p0x) * invx, a1 = (1.0f - p0x) * invx;
  float axmin = fminf(a0, a1), axmax = fmaxf(a0, a1);
  a0 = (-1.0f - p0y) * invy; a1 = (1.0f - p0y) * invy;
  float aymin = fminf(a0, a1), aymax = fmaxf(a0, a1);
  a0 = (-1.0f - p0z) * invz; a1 = (1.0f - p0z) * invz;
  float azmin = fminf(a0, a1), azmax = fmaxf(a0, a1);
  amin = fmaxf(fmaxf(axmin, aymin), fmaxf(azmin, 0.0f));
  amax = fminf(fminf(axmax, aymax), fminf(azmax, 1.0f));
}

// --- image fp32 -> fp16 ------------------------------------------------------
__global__ __launch_bounds__(256) void convert_h(
    const float* __restrict__ img, __half* __restrict__ h)
{
  int i = blockIdx.x * blockDim.x + threadIdx.x;
  int stride = gridDim.x * blockDim.x;
  for (; i < NVOX; i += stride) h[i] = __float2half(img[i]);
}

// --- sort pass 1: keys + per-block histogram (LDS ballot, no global atomics) -
__global__ __launch_bounds__(256) void ray_keys(
    const float* __restrict__ lors, int n, int nblk,
    int* __restrict__ keys, int* __restrict__ bhist)
{
  __shared__ int lhist[NBINS];
  if (threadIdx.x < NBINS) lhist[threadIdx.x] = 0;
  __syncthreads();

  int i = blockIdx.x * blockDim.x + threadIdx.x;
  int bin = -1;
  if (i < n) {
    float p0x,p0y,p0z,dx,dy,dz,dsx,dsy,dsz,invx,invy,invz,amin,amax;
    ray_setup(lors + (long)i * 6, p0x,p0y,p0z, dx,dy,dz,
              dsx,dsy,dsz, invx,invy,invz, amin,amax);
    bin = 0;
    if (amax > amin) {
      int st, iv, c0, c1, c2; float al, da;
      axis_init(amin, amax, p0x, dsx, invx, st, iv, al, da, c0);
      axis_init(amin, amax, p0y, dsy, invy, st, iv, al, da, c1);
      axis_init(amin, amax, p0z, dsz, invz, st, iv, al, da, c2);
      int V = c0 + c1 + c2;            // <= 387 -> V>>6 <= 6
      bin = 1 + (V >> 6);
    }
    keys[i] = bin;
  }
  int lane = threadIdx.x & 63;
#pragma unroll
  for (int b = 0; b < NBINS; ++b) {
    unsigned long long m = __ballot(bin == b);
    if (lane == 0 && m) atomicAdd(&lhist[b], (int)__popcll(m));
  }
  __syncthreads();
  if (threadIdx.x < NBINS)
    bhist[threadIdx.x * nblk + blockIdx.x] = lhist[threadIdx.x];
}

// --- sort pass 2: per-bin exclusive scan over blocks + bin bases -------------
// one block, 256 threads; wave w handles bins w and w+4.
__global__ __launch_bounds__(256) void scan_bins(
    int* __restrict__ bhist, int nblk, int* __restrict__ base)
{
  __shared__ int tot[NBINS];
  int w = threadIdx.x >> 6, lane = threadIdx.x & 63;
  for (int bin = w; bin < NBINS; bin += 4) {
    int run = 0;
    for (int c0 = 0; c0 < nblk; c0 += 64) {
      int b = c0 + lane;
      int v = (b < nblk) ? bhist[bin * nblk + b] : 0;
      int p = v;
#pragma unroll
      for (int d = 1; d < 64; d <<= 1) {
        int o = __shfl_up(p, d);
        if (lane >= d) p += o;
      }
      if (b < nblk) bhist[bin * nblk + b] = run + (p - v);
      run += __shfl(p, 63);
    }
    if (lane == 0) tot[bin] = run;
  }
  __syncthreads();
  if (threadIdx.x == 0) {
    int run = 0;
    for (int r = 0; r < NBINS; ++r) {
      int bin = (r < NBINS - 1) ? (NBINS - 1 - r) : 0;   // 7,6,...,1,0
      base[bin] = run; run += tot[bin];
    }
  }
}

// --- sort pass 3: deterministic rank-based scatter ---------------------------
__global__ __launch_bounds__(256) void scatter_perm(
    const int* __restrict__ keys, const int* __restrict__ bhist,
    const int* __restrict__ base, int* __restrict__ perm, int n, int nblk)
{
  __shared__ int wcnt[4][NBINS];
  __shared__ int woff[4][NBINS];
  int i = blockIdx.x * blockDim.x + threadIdx.x;
  int w = threadIdx.x >> 6, lane = threadIdx.x & 63;
  int bin = (i < n) ? keys[i] : -1;
  unsigned long long lt = ((unsigned long long)1 << lane) - 1ull;
  int rank = 0;
#pragma unroll
  for (int b = 0; b < NBINS; ++b) {
    unsigned long long m = __ballot(bin == b);
    if (bin == b) rank = (int)__popcll(m & lt);
    if (lane == 0) wcnt[w][b] = (int)__popcll(m);
  }
  __syncthreads();
  if (threadIdx.x < NBINS) {
    int b = threadIdx.x, r = 0;
    for (int ww = 0; ww < 4; ++ww) { woff[ww][b] = r; r += wcnt[ww][b]; }
  }
  __syncthreads();
  if (i < n) {
    int pos = base[bin] + bhist[bin * nblk + blockIdx.x] + woff[w][bin] + rank;
    perm[pos] = i;
  }
}

// --- traversal ---------------------------------------------------------------
__global__ __launch_bounds__(256) void siddon_fp(
    const __half* __restrict__ image,
    const float* __restrict__ lors,
    float* __restrict__ out,
    const int* __restrict__ perm, int n)
{
  int t    = blockIdx.x * blockDim.x + threadIdx.x;
  int slot = t >> LOGK;
  int k    = t & (K - 1);
  if (slot >= n) return;
  int ray  = perm ? perm[slot] : slot;

  float p0x,p0y,p0z,dx,dy,dz,dsx,dsy,dsz,invx,invy,invz,amin,amax;
  ray_setup(lors + (long)ray * 6, p0x,p0y,p0z, dx,dy,dz,
            dsx,dsy,dsz, invx,invy,invz, amin,amax);

  float acc0 = 0.0f, acc1 = 0.0f;
  if (amax > amin) {
    float s      = (amax - amin) * (1.0f / (float)K);
    float astart = fmaf((float)k, s, amin);
    float aend   = (k == K - 1) ? amax : fmaf((float)(k + 1), s, amin);

    TState S;
    S.acur = astart; S.aend = aend;
    int stx, sty, stz, ivx, ivy, ivz, c0, c1, c2;
    axis_init(astart, aend, p0x, dsx, invx, stx, ivx, S.alx, S.dax, c0);
    axis_init(astart, aend, p0y, dsy, invy, sty, ivy, S.aly, S.day, c1);
    axis_init(astart, aend, p0z, dsz, invz, stz, ivz, S.alz, S.daz, c2);
    // ARITHMETIC packing (not OR): exact for transient -1 excursions (r9).
    S.idx = ivx * 32768 + ivy * 256 + ivz * 2;
    S.dix = stx * 32768;  S.diy = sty * 256;  S.diz = stz * 2;

    int ns = c0 + c1 + c2 + 2;          // segments = crossings+1, +1 margin
    int nb = (ns + 3) >> 2;             // batches of 4
    if (nb < 2) nb = 2;                 // prologue needs two batches

    float difA[4], difB[4], difC[4];
    float vA[4], vB[4], vC[4];

#define ISSUE(X)   step4(image, S, dif##X, v##X)
#define CONSUME(X)                                                  \
    do { acc0 = fmaf(dif##X[0], v##X[0], acc0);                     \
         acc1 = fmaf(dif##X[1], v##X[1], acc1);                     \
         acc0 = fmaf(dif##X[2], v##X[2], acc0);                     \
         acc1 = fmaf(dif##X[3], v##X[3], acc1); } while (0)

    ISSUE(A);
    ISSUE(B);
    int produce = nb - 2;
    while (produce >= 3) {
      ISSUE(C); CONSUME(A);
      ISSUE(A); CONSUME(B);
      ISSUE(B); CONSUME(C);
      produce -= 3;
    }
    if (produce == 2) {
      ISSUE(C); CONSUME(A);
      ISSUE(A); CONSUME(B);
      CONSUME(C); CONSUME(A);
    } else if (produce == 1) {
      ISSUE(C); CONSUME(A);
      CONSUME(B); CONSUME(C);
    } else {
      CONSUME(A); CONSUME(B);
    }
#undef ISSUE
#undef CONSUME

    float rlen = sqrtf(dx * dx + dy * dy + dz * dz);
    acc0 = (acc0 + acc1) * rlen;
    acc1 = 0.0f;
  }

  float acc = acc0 + acc1;
  acc += __shfl_xor(acc, 1);
  acc += __shfl_xor(acc, 2);
  acc += __shfl_xor(acc, 4);
  acc += __shfl_xor(acc, 8);
  if (k == 0) out[ray] = acc;
}

extern "C" void kernel_launch(void* const* d_in, const int* in_sizes, int n_in,
                              void* d_out, int out_size, void* d_ws, size_t ws_size,
                              hipStream_t stream) {
  const float* image = (const float*)d_in[0];   // [128,128,128] f32
  const float* lors  = (const float*)d_in[1];   // [N,6] f32
  float* out = (float*)d_out;                   // [N] f32
  int n = out_size;
  int nblk = (n + 255) / 256;

  // ws layout: fp16 image (4 MB) | keys[n] | perm[n] | bhist[8*nblk] | base[8]
  char* p = (char*)d_ws;
  __half* h   = (__half*)p;                       p += (size_t)NVOX * 2;
  int* keys   = (int*)p;                          p += (size_t)n * 4;
  int* perm   = (int*)p;                          p += (size_t)n * 4;
  int* bhist  = (int*)p;                          p += (size_t)NBINS * nblk * 4;
  int* base   = (int*)p;                          p += NBINS * 4;
  size_t need = (size_t)(p - (char*)d_ws);

  hipLaunchKernelGGL(convert_h, dim3(2048), dim3(256), 0, stream, image, h);

  int* permArg = nullptr;
  if (ws_size >= need) {
    hipLaunchKernelGGL(ray_keys,     dim3(nblk), dim3(256), 0, stream,
                       lors, n, nblk, keys, bhist);
    hipLaunchKernelGGL(scan_bins,    dim3(1),    dim3(256), 0, stream,
                       bhist, nblk, base);
    hipLaunchKernelGGL(scatter_perm, dim3(nblk), dim3(256), 0, stream,
                       keys, bhist, base, perm, n, nblk);
    permArg = perm;
  }

  long total = (long)n * K;
  int block = 256;
  int grid = (int)((total + block - 1) / block);
  hipLaunchKernelGGL(siddon_fp, dim3(grid), dim3(block), 0, stream,
                     h, lors, out, permArg, n);
}